// Round 17
// baseline (602.696 us; speedup 1.0000x reference)
//
#include <hip/hip_runtime.h>
#include <cstdint>

#define TS 16384           // elements per tile (stream-relative)
#define NSLOT 13           // binade slots per chain; miss => exact span fallback
#define NCH 7
#define NW 4096            // wave-segments for partition (proven R15 config)

// chains: 0:s(-2) 1:s(-1) 2:s(+1) 3:q(-2) 4:q(-1) 5:q(0) 6:q(+1)
// s(0) non-stalling -> f64 in diag; counts -> min(true, 2^24)

// ---- exact f32 bin boundaries via bit-bisection on the np predicate ----
__device__ __forceinline__ void f32_bounds(float a, float& B1, float& B2) {
    unsigned lo = __float_as_uint(__fmul_rn(a, 0.49f));
    unsigned hi = __float_as_uint(__fmul_rn(a, 0.51f));
    while (hi - lo > 1u) {
        const unsigned mid = lo + ((hi - lo) >> 1);
        if (__fdiv_rn(__uint_as_float(mid), a) <= 0.5f) lo = mid; else hi = mid;
    }
    B1 = __uint_as_float(lo);
    lo = __float_as_uint(__fmul_rn(a, 1.49f));
    hi = __float_as_uint(__fmul_rn(a, 1.51f));
    while (hi - lo > 1u) {
        const unsigned mid = lo + ((hi - lo) >> 1);
        if (__fdiv_rn(__uint_as_float(mid), a) < 1.5f) lo = mid; else hi = mid;
    }
    B2 = __uint_as_float(hi);
}

__device__ __forceinline__ int kbin_f(float x, float B1, float B2) {
    if (x >   B1) return 1;
    if (x >= -B1) return 0;
    if (x >  -B2) return -1;
    return -2;
}

__device__ __forceinline__ double wred64(double v) {
#pragma unroll
    for (int d = 32; d >= 1; d >>= 1) v += __shfl_xor(v, d, 64);
    return v;
}
__device__ __forceinline__ int wred32i(int v) {
#pragma unroll
    for (int d = 32; d >= 1; d >>= 1) v += __shfl_xor(v, d, 64);
    return v;
}

__device__ __forceinline__ int expo_bits(double A) {
    const long long b = __double_as_longlong(A);
    return (int)((b >> 52) & 0x7FF) - 1023;
}
__device__ __forceinline__ int emin_of(double A0) {
    if (!(A0 > 0.0)) return 12345;           // invalid -> walker always spans (exact)
    const int e = expo_bits(A0);
    if (e < -100 || e > 100) return 12345;
    return e;
}

// ---- part1: 4 waves/block, wave-private segments, no barriers, no atomics ----
__global__ __launch_bounds__(256) void part1(const float* __restrict__ w,
        const float* __restrict__ alpha, int* __restrict__ hist,
        double* __restrict__ dpart, long long n, long long nsegw)
{
    const float a = alpha[0];
    float B1, B2;
    f32_bounds(a, B1, B2);
    const int wv = threadIdx.x >> 6, lane = threadIdx.x & 63;
    const int sid = blockIdx.x * 4 + wv;
    const long long seg = (long long)sid * nsegw;
    long long send = seg + nsegw; if (send > n) send = n;
    int h0=0,h1=0,h2=0,h3=0;
    double ad=0.0, dd=0.0, s0=0.0;

    for (long long base = seg; base < send; base += 256) {
        const long long i = base + (long long)lane * 4;
        if (i >= send) break;
        float4 v;
        if (i + 3 < send) v = *reinterpret_cast<const float4*>(w + i);
        else {
            v = make_float4(0.f,0.f,0.f,0.f);
            v.x = w[i];
            if (i+1 < send) v.y = w[i+1];
            if (i+2 < send) v.z = w[i+2];
        }
        const float xs[4] = {v.x, v.y, v.z, v.w};
        const int nv = (int)((send - i) < 4 ? (send - i) : 4);
#pragma unroll
        for (int j = 0; j < 4; ++j) {
            if (j >= nv) break;
            const float x = xs[j];
            const int k = kbin_f(x, B1, B2);
            h0 += (k==-2); h1 += (k==-1); h2 += (k==0); h3 += (k==1);
            const float bf = (float)k;
            const float wq = __fmul_rn(bf, a);
            const float d  = __fsub_rn(x, wq);
            ad += (double)fabsf(d);
            dd += (double)__fmul_rn(d, d);
            if (k == 0) s0 += (double)x;
        }
    }

    h0 = wred32i(h0); h1 = wred32i(h1); h2 = wred32i(h2); h3 = wred32i(h3);
    ad = wred64(ad);  dd = wred64(dd);  s0 = wred64(s0);

    if (lane == 0) {
        hist[sid*4 + 0] = h0;
        hist[sid*4 + 1] = h1;
        hist[sid*4 + 2] = h2;
        hist[sid*4 + 3] = h3;
        dpart[sid*4 + 0] = ad;
        dpart[sid*4 + 1] = dd;
        dpart[sid*4 + 2] = s0;
    }
}

// ---- scank: scan histograms + reduce diag partials ----
__global__ __launch_bounds__(256) void scank(const int* __restrict__ hist,
        const double* __restrict__ dpart, int* __restrict__ bbase,
        int* __restrict__ hdr, double* __restrict__ diag)
{
    const int wv = threadIdx.x >> 6, lane = threadIdx.x & 63;
    if (wv < 4) {
        int running = 0;
        for (int c = 0; c < NW/64; ++c) {
            int v = hist[(c*64 + lane)*4 + wv];
            int p = v;
#pragma unroll
            for (int d = 1; d < 64; d <<= 1) {
                int t = __shfl_up(p, d, 64);
                if (lane >= d) p += t;
            }
            bbase[(c*64+lane)*4 + wv] = running + p - v;
            running += __shfl(p, 63, 64);
        }
        if (lane == 0) hdr[wv] = running;      // cnt[b]
    }
    __syncthreads();
    if (threadIdx.x == 0) {                     // base[b], 64-elem aligned
        int b = 0;
        for (int q = 0; q < 4; ++q) { hdr[4+q] = b; b += (hdr[q] + 63) & ~63; }
    }

    // diag partial reduction (ad, dd, s0)
    double a0=0.0, a1=0.0, a2=0.0;
    for (int e = threadIdx.x; e < NW; e += 256) {
        a0 += dpart[e*4+0]; a1 += dpart[e*4+1]; a2 += dpart[e*4+2];
    }
    a0 = wred64(a0); a1 = wred64(a1); a2 = wred64(a2);
    __shared__ double dsh[4][3];
    if (lane == 0) { dsh[wv][0]=a0; dsh[wv][1]=a1; dsh[wv][2]=a2; }
    __syncthreads();
    if (threadIdx.x == 0) {
        diag[0] = dsh[0][0]+dsh[1][0]+dsh[2][0]+dsh[3][0];
        diag[1] = dsh[0][1]+dsh[1][1]+dsh[2][1]+dsh[3][1];
        diag[2] = dsh[0][2]+dsh[1][2]+dsh[2][2]+dsh[3][2];
    }
}

// ---- part2: direct ranked global writes (proven R14/R15); half-grid via sid_base ----
__global__ __launch_bounds__(256) void part2(const float* __restrict__ w,
        const float* __restrict__ alpha, const int* __restrict__ bbase,
        const int* __restrict__ hdr, float* __restrict__ streams,
        long long n, long long nsegw, int sid_base)
{
    const float a = alpha[0];
    float B1, B2;
    f32_bounds(a, B1, B2);
    const int wv = threadIdx.x >> 6, lane = threadIdx.x & 63;
    const int sid = sid_base + blockIdx.x * 4 + wv;
    const unsigned long long ltmask = (1ULL << lane) - 1ULL;

    int run0 = hdr[4+0] + bbase[sid*4 + 0];
    int run1 = hdr[4+1] + bbase[sid*4 + 1];
    int run2 = hdr[4+2] + bbase[sid*4 + 2];
    int run3 = hdr[4+3] + bbase[sid*4 + 3];

    const long long seg = (long long)sid * nsegw;
    long long send = seg + nsegw; if (send > n) send = n;

    for (long long base = seg; base < send; base += 256) {
        const long long i = base + (long long)lane * 4;
        float xs[4]; int kk[4];
        if (i + 3 < send) {
            const float4 v = *reinterpret_cast<const float4*>(w + i);
            xs[0]=v.x; xs[1]=v.y; xs[2]=v.z; xs[3]=v.w;
            kk[0]=kbin_f(xs[0],B1,B2); kk[1]=kbin_f(xs[1],B1,B2);
            kk[2]=kbin_f(xs[2],B1,B2); kk[3]=kbin_f(xs[3],B1,B2);
        } else {
#pragma unroll
            for (int j = 0; j < 4; ++j) {
                const long long idx = i + j;
                if (idx < send) { xs[j] = w[idx]; kk[j] = kbin_f(xs[j],B1,B2); }
                else            { xs[j] = 0.f;   kk[j] = 9; }
            }
        }

        int br0=0,br1=0,br2=0,br3=0;
        int tt0=0,tt1=0,tt2=0,tt3=0;
#pragma unroll
        for (int j = 0; j < 4; ++j) {
            const unsigned long long b0 = __ballot(kk[j] == -2);
            const unsigned long long b1 = __ballot(kk[j] == -1);
            const unsigned long long b2 = __ballot(kk[j] ==  0);
            const unsigned long long b3 = __ballot(kk[j] ==  1);
            br0 += __popcll(b0 & ltmask); tt0 += __popcll(b0);
            br1 += __popcll(b1 & ltmask); tt1 += __popcll(b1);
            br2 += __popcll(b2 & ltmask); tt2 += __popcll(b2);
            br3 += __popcll(b3 & ltmask); tt3 += __popcll(b3);
        }

        int own0=0, own1=0, own2=0, own3=0;
#pragma unroll
        for (int j = 0; j < 4; ++j) {
            const int k = kk[j];
            if      (k == -2) { streams[(long long)(run0 + br0 + own0)] = xs[j]; ++own0; }
            else if (k == -1) { streams[(long long)(run1 + br1 + own1)] = xs[j]; ++own1; }
            else if (k ==  0) { streams[(long long)(run2 + br2 + own2)] = xs[j]; ++own2; }
            else if (k ==  1) { streams[(long long)(run3 + br3 + own3)] = xs[j]; ++own3; }
        }
        run0 += tt0; run1 += tt1; run2 += tt2; run3 += tt3;
    }
}

// ---- exact span walker on a stream (proven R9..R15, verbatim) ----
__device__ void span_st(const float* __restrict__ p, int isq,
                        double& A, long long lo, long long hi, int lane)
{
    for (long long base = lo; base < hi; base += 4096) {
        float xs[64];
        const long long e0 = base + (long long)lane * 64;
#pragma unroll
        for (int q4 = 0; q4 < 16; ++q4) {
            const long long fi = e0 + q4 * 4;
            float4 v = make_float4(0.f,0.f,0.f,0.f);
            if (fi + 3 < hi) v = *reinterpret_cast<const float4*>(p + fi);
            else {
                if (fi     < hi) v.x = p[fi];
                if (fi + 1 < hi) v.y = p[fi + 1];
                if (fi + 2 < hi) v.z = p[fi + 2];
            }
            xs[q4*4+0]=v.x; xs[q4*4+1]=v.y; xs[q4*4+2]=v.z; xs[q4*4+3]=v.w;
        }
#pragma unroll
        for (int j = 0; j < 64; ++j) {
            const float x = xs[j];
            xs[j] = isq ? __fmul_rn(x, x) : fabsf(x);
        }

        int C = 0;
        while (C < 64) {
            if (A > 0.0) {
                const int e = ilogb(A);
                const double u  = ldexp(1.0, e - 23);
                const double Bb = ldexp(1.0, e + 1);
                const double sc = ldexp(1.0, 23 - e);
                double kd = 0.0;
                if (lane >= C) {
#pragma unroll
                    for (int j = 0; j < 64; ++j) kd += rint((double)xs[j] * sc);
                }
                const bool big = kd >= 1099511627776.0;   // 2^40
                double pp = kd;
#pragma unroll
                for (int d = 1; d < 64; d <<= 1) {
                    double tt = __shfl_up(pp, d, 64);
                    if (lane >= d) pp += tt;
                }
                const bool cross = (lane >= C) && (big || (A + u * pp >= Bb));
                const unsigned long long bal = __ballot(cross);
                if (bal == 0ULL) {
                    A = A + u * __shfl(pp, 63);
                    break;
                }
                const int F = __ffsll((long long)bal) - 1;
                double An = 0.0;
                if (lane == F) {
                    const double Aex = A + u * (pp - kd);
                    float Af = (float)Aex;
#pragma unroll
                    for (int j = 0; j < 64; ++j) Af = __fadd_rn(Af, xs[j]);
                    An = (double)Af;
                }
                A = __shfl(An, F);
                C = F + 1;
            } else {
                bool has = false;
                if (lane >= C) {
#pragma unroll
                    for (int j = 0; j < 64; ++j) has = has || (xs[j] > 0.0f);
                }
                const unsigned long long bal = __ballot(has);
                if (bal == 0ULL) break;
                const int F = __ffsll((long long)bal) - 1;
                double An = 0.0;
                if (lane == F) {
                    float Af = 0.0f;
#pragma unroll
                    for (int j = 0; j < 64; ++j) Af = __fadd_rn(Af, xs[j]);
                    An = (double)Af;
                }
                A = __shfl(An, F);
                C = F + 1;
            }
        }
    }
}

// ---------------- span0: exact tile-0 chain state per chain ----------------
__global__ __launch_bounds__(64) void span0(const float* __restrict__ streams,
        const int* __restrict__ hdr, double* __restrict__ A0d)
{
    const int ch = blockIdx.x;
    const int STR[NCH] = {0,1,3,0,1,2,3};
    const int ISQ[NCH] = {0,0,0,1,1,1,1};
    const int st = STR[ch];
    const long long cnt = (long long)hdr[st];
    const float* p = streams + hdr[4+st];
    double A = 0.0;
    if (cnt > 0)
        span_st(p, ISQ[ch], A, 0LL, (TS < cnt ? (long long)TS : cnt), threadIdx.x);
    if (threadIdx.x == 0) A0d[ch] = A;
}

// ---- passA: fused s+q per stream, 13 slots, FLOAT accumulators ----
template<int HASS>
__device__ __forceinline__ void passA_two(const float* __restrict__ p,
        long long cnt, double* __restrict__ krowS, double* __restrict__ krowQ,
        float baseS, float baseQ, long long ntg, long long tile)
{
    const long long lo = tile * TS;
    long long hi = lo + TS; if (hi > cnt) hi = cnt;

    float scS[NSLOT], scQ[NSLOT];
    scS[0] = baseS; scQ[0] = baseQ;
#pragma unroll
    for (int s = 1; s < NSLOT; ++s) { scS[s] = scS[s-1]*0.5f; scQ[s] = scQ[s-1]*0.5f; }
    float accS[NSLOT], accQ[NSLOT];
#pragma unroll
    for (int s = 0; s < NSLOT; ++s) { accS[s] = 0.f; accQ[s] = 0.f; }

    const int tid = threadIdx.x;
    for (long long i = lo + (long long)tid*4; i < hi; i += 256*4) {
        float4 v;
        if (i + 3 < hi) v = *reinterpret_cast<const float4*>(p + i);
        else {
            v = make_float4(0.f,0.f,0.f,0.f);
            v.x = p[i];
            if (i+1 < hi) v.y = p[i+1];
            if (i+2 < hi) v.z = p[i+2];
        }
        const float xsv[4] = {v.x, v.y, v.z, v.w};
#pragma unroll
        for (int j = 0; j < 4; ++j) {
            const float x  = xsv[j];
            const float xq = __fmul_rn(x, x);
            if (HASS) {
                const float ax = fabsf(x);
#pragma unroll
                for (int s = 0; s < NSLOT; ++s)
                    accS[s] += rintf(ax * scS[s]);
            }
#pragma unroll
            for (int s = 0; s < NSLOT; ++s)
                accQ[s] += rintf(xq * scQ[s]);
        }
    }

    __shared__ double lred[4][2*NSLOT];
    const int lane = tid & 63, wv = tid >> 6;
#pragma unroll
    for (int s = 0; s < NSLOT; ++s) {
        double rs = wred64((double)accS[s]);
        double rq = wred64((double)accQ[s]);
        if (lane == 0) { lred[wv][s] = rs; lred[wv][NSLOT+s] = rq; }
    }
    __syncthreads();
    if (tid < 2*NSLOT) {
        const double sum = lred[0][tid]+lred[1][tid]+lred[2][tid]+lred[3][tid];
        if (tid < NSLOT) {
            if (HASS) krowS[(long long)tid * ntg + tile] = sum;
        } else {
            krowQ[(long long)(tid-NSLOT) * ntg + tile] = sum;
        }
    }
}

__global__ __launch_bounds__(256) void passA7(const float* __restrict__ streams,
        const int* __restrict__ hdr, const double* __restrict__ A0d,
        double* __restrict__ Ktab, long long ntg)
{
    const int st = blockIdx.y;                    // stream 0..3
    const int SCH[4] = {0, 1, -1, 2};             // s-chain per stream
    const int QCH[4] = {3, 4,  5, 6};             // q-chain per stream
    const long long cnt = (long long)hdr[st];
    const long long tile = blockIdx.x;
    if (tile * TS >= cnt) return;
    const float* p = streams + hdr[4+st];

    const int qch = QCH[st];
    const int emQ = emin_of(A0d[qch]);
    const float baseQ = (emQ == 12345) ? 0.0f : ldexpf(1.0f, 23 - emQ);
    double* krowQ = Ktab + (long long)qch * NSLOT * ntg;

    if (SCH[st] >= 0) {
        const int sch = SCH[st];
        const int emS = emin_of(A0d[sch]);
        const float baseS = (emS == 12345) ? 0.0f : ldexpf(1.0f, 23 - emS);
        double* krowS = Ktab + (long long)sch * NSLOT * ntg;
        passA_two<1>(p, cnt, krowS, krowQ, baseS, baseQ, ntg, tile);
    } else {
        passA_two<0>(p, cnt, nullptr, krowQ, 0.0f, baseQ, ntg, tile);
    }
}

// ---- walk: windowed binade walk, 128-tile windows (proven R15) ----
__global__ __launch_bounds__(64) void walk2(const float* __restrict__ streams,
        const int* __restrict__ hdr, const double* __restrict__ A0d,
        const double* __restrict__ Ktab, float* __restrict__ chains, long long ntg)
{
    const int ch = blockIdx.x;
    const int lane = threadIdx.x;
    const int STR[NCH]  = {0,1,3,0,1,2,3};
    const int ISQ[NCH]  = {0,0,0,1,1,1,1};
    const int OSLOT[NCH]= {0,1,3,4,5,6,7};
    const int st = STR[ch], isq = ISQ[ch];
    const long long cnt = (long long)hdr[st];
    const float* p = streams + hdr[4+st];
    const long long ntiles = (cnt + TS - 1) / TS;
    const double* krow = Ktab + (long long)ch * NSLOT * ntg;
    const int em = emin_of(A0d[ch]);

    double A = A0d[ch];
    long long t = 1;
    while (t < ntiles) {
        if (A > 0.0 && em != 12345) {
            const int e = expo_bits(A);
            const int slot = e - em;
            if (slot >= 0 && slot < NSLOT) {
                const long long wt0 = t + lane;
                const long long wt1 = t + 64 + lane;
                double Kv0 = (wt0 < ntiles) ? krow[(long long)slot * ntg + wt0] : 0.0;
                double Kv1 = (wt1 < ntiles) ? krow[(long long)slot * ntg + wt1] : 0.0;
                double P0 = Kv0;
#pragma unroll
                for (int d = 1; d < 64; d <<= 1) {
                    double tt = __shfl_up(P0, d, 64);
                    if (lane >= d) P0 += tt;
                }
                const double tot0 = __shfl(P0, 63);
                double P1 = Kv1;
#pragma unroll
                for (int d = 1; d < 64; d <<= 1) {
                    double tt = __shfl_up(P1, d, 64);
                    if (lane >= d) P1 += tt;
                }
                P1 += tot0;
                const double u  = ldexp(1.0, e - 23);
                const double Bb = ldexp(1.0, e + 1);
                const unsigned long long bal0 = __ballot(A + u * P0 > Bb);
                const unsigned long long bal1 = __ballot(A + u * P1 > Bb);
                if (bal0 == 0ULL && bal1 == 0ULL) {      // whole 128 consumable: exact
                    A += u * __shfl(P1, 63);
                    t += 128;
                    continue;
                }
                const int F = (bal0 != 0ULL) ? (__ffsll((long long)bal0) - 1)
                                             : (64 + __ffsll((long long)bal1) - 1);
                if (F > 0) {                              // consume tiles t..t+F-1
                    const double cv = (F <= 64) ? __shfl(P0, F - 1)
                                                : __shfl(P1, F - 65);
                    A += u * cv;
                    t += F;
                }
                const long long lo = t * (long long)TS;   // crossing tile: exact
                long long hi = lo + TS; if (hi > cnt) hi = cnt;
                span_st(p, isq, A, lo, hi, lane);
                ++t;
                continue;
            }
        }
        const long long lo = t * (long long)TS;
        long long hi = lo + TS; if (hi > cnt) hi = cnt;
        span_st(p, isq, A, lo, hi, lane);
        ++t;
    }
    if (lane == 0) chains[OSLOT[ch]] = (float)A;
}

// ---------------- finalize (proven R9..R15) ----------------
__global__ void fin2(const float* __restrict__ chains,
                     const double* __restrict__ diag,
                     const int* __restrict__ hdr,
                     const float* __restrict__ alpha,
                     float* __restrict__ out, long long n)
{
    const float a = alpha[0];
    const float s_np[4]  = { -chains[0], -chains[1], (float)diag[2], chains[3] };
    const float sq_np[4] = {  chains[4],  chains[5],  chains[6],     chains[7] };
    float tmse = 0.f, tvar = 0.f;
#pragma unroll
    for (int b = 0; b < 4; ++b) {
        float cnt = fminf((float)hdr[b], 16777216.0f);
        float safe = fmaxf(cnt, 1.0f);
        float mean = __fdiv_rn(s_np[b], safe);
        float var  = __fsub_rn(__fdiv_rn(sq_np[b], safe), __fmul_rn(mean, mean));
        float lvl  = __fmul_rn((float)(b - 2), a);
        float e    = __fsub_rn(mean, lvl);
        if (cnt > 0.f)  tmse = __fadd_rn(tmse, __fmul_rn(e, e));
        if (cnt >= 2.f) tvar = __fadd_rn(tvar, var);
    }
    out[0] = __fadd_rn(tmse, tvar);
    out[1] = tmse;
    out[2] = tvar;
    out[3] = (float)(diag[1] / (double)n);
    out[4] = (float)(diag[0] / (double)n);
}

// ================= TIER 3: R6 bit-exact serial fallback =================
__global__ __launch_bounds__(64) void zero_diag6(double* __restrict__ diag) {
    if (threadIdx.x < 6) diag[threadIdx.x] = 0.0;
}
__global__ __launch_bounds__(256) void diag6(const float* __restrict__ w,
        const float* __restrict__ alpha, double* __restrict__ diag, int n4, long long n)
{
    const float a = alpha[0];
    float ad = 0.f, dd = 0.f; int c0=0,c1=0,c2=0,c3=0;
    auto pe = [&](float x) {
        float r = __fdiv_rn(x, a);
        float cl = fminf(1.0f, fmaxf(-2.0f, r));
        float bf = rintf(cl); int k = (int)bf;
        float wq = __fmul_rn(bf, a); float d = __fsub_rn(x, wq);
        ad = __fadd_rn(ad, fabsf(d)); dd = __fadd_rn(dd, __fmul_rn(d, d));
        if (k==-2) c0++; else if (k==-1) c1++; else if (k==0) c2++; else c3++;
    };
    const float4* w4 = reinterpret_cast<const float4*>(w);
    const int stride = gridDim.x * 256;
    for (int i = blockIdx.x * 256 + threadIdx.x; i < n4; i += stride) {
        float4 v = w4[i]; pe(v.x); pe(v.y); pe(v.z); pe(v.w);
    }
    if (blockIdx.x == 0 && threadIdx.x == 0)
        for (long long i = (long long)n4 * 4; i < n; ++i) pe(w[i]);
    double vals[6] = {(double)ad,(double)dd,(double)c0,(double)c1,(double)c2,(double)c3};
    __shared__ double red[256];
    const int tid = threadIdx.x;
#pragma unroll
    for (int j = 0; j < 6; ++j) {
        red[tid] = vals[j]; __syncthreads();
        for (int s = 128; s > 0; s >>= 1) { if (tid < s) red[tid] += red[tid+s]; __syncthreads(); }
        if (tid == 0) atomicAdd(&diag[j], red[0]);
        __syncthreads();
    }
}
__global__ __launch_bounds__(64) void seq_chains(const float* __restrict__ w,
        const float* __restrict__ alpha, float* __restrict__ chains, long long n)
{
    const float a = alpha[0];
    const int lane = threadIdx.x; const int myrow = lane & 7;
    __shared__ float val[8][64];
    float acc = 0.0f;
    const long long ntl = (n + 63) / 64;
    float x_next = (lane < n) ? w[lane] : 0.0f;
    for (long long t = 0; t < ntl; ++t) {
        float x = x_next;
        { long long idxn = (t + 1) * 64 + lane; x_next = (idxn < n) ? w[idxn] : 0.0f; }
        const long long idx = t * 64 + lane;
        const bool valid = (idx < n);
        float r = __fdiv_rn(x, a);
        float cl = fminf(1.0f, fmaxf(-2.0f, r));
        int k = (int)rintf(cl); int row = k + 2;
        float xx = __fmul_rn(x, x);
#pragma unroll
        for (int b = 0; b < 4; ++b) {
            val[b][lane]     = (valid && row == b) ? x  : 0.0f;
            val[4 + b][lane] = (valid && row == b) ? xx : 0.0f;
        }
        __syncthreads();
        if (lane < 8) {
#pragma unroll
            for (int e4i = 0; e4i < 16; ++e4i) {
                float4 v = *reinterpret_cast<const float4*>(&val[myrow][e4i * 4]);
                acc = __fadd_rn(acc, v.x); acc = __fadd_rn(acc, v.y);
                acc = __fadd_rn(acc, v.z); acc = __fadd_rn(acc, v.w);
            }
        }
        __syncthreads();
    }
    if (lane < 8) chains[lane] = acc;
}
__global__ void fin_seq(const float* __restrict__ chains, const double* __restrict__ diag,
                        const float* __restrict__ alpha, float* __restrict__ out, long long n)
{
    const float a = alpha[0];
    float tmse = 0.0f, tvar = 0.0f;
#pragma unroll
    for (int b = 0; b < 4; ++b) {
        float cnt = fminf((float)diag[2 + b], 16777216.0f);
        float safe = fmaxf(cnt, 1.0f);
        float mean = __fdiv_rn(chains[b], safe);
        float var  = __fsub_rn(__fdiv_rn(chains[4 + b], safe), __fmul_rn(mean, mean));
        float lvl  = __fmul_rn((float)(b - 2), a);
        float e    = __fsub_rn(mean, lvl);
        if (cnt > 0.0f)  tmse = __fadd_rn(tmse, __fmul_rn(e, e));
        if (cnt >= 2.0f) tvar = __fadd_rn(tvar, var);
    }
    out[0] = __fadd_rn(tmse, tvar);
    out[1] = tmse; out[2] = tvar;
    out[3] = (float)(diag[1] / (double)n);
    out[4] = (float)(diag[0] / (double)n);
}

// ---------------- launcher ----------------
extern "C" void kernel_launch(void* const* d_in, const int* in_sizes, int n_in,
                              void* d_out, int out_size, void* d_ws, size_t ws_size,
                              hipStream_t stream) {
    const float* w     = (const float*)d_in[0];
    const float* alpha = (const float*)d_in[1];
    float* out = (float*)d_out;
    const long long n = (long long)in_sizes[0];
    const long long ntg = (n + TS - 1) / TS;

    size_t off = 0;
    const size_t ktab_off = off;   off += (size_t)NCH * NSLOT * ntg * 8;
    const size_t hist_off = off;   off += (size_t)NW * 4 * 4;
    const size_t bbase_off = off;  off += (size_t)NW * 4 * 4;
    const size_t hdr_off = off;    off += 8 * 4;
    const size_t diag_off = (off + 7) & ~(size_t)7;  off = diag_off + 8 * 8;
    const size_t dpart_off = off;  off += (size_t)NW * 4 * 8;
    const size_t a0_off = off;     off += 8 * 8;
    const size_t chains_off = off; off += 8 * 4;
    const size_t streams_off = (off + 255) & ~(size_t)255;
    const size_t need1 = streams_off + ((size_t)n + 512) * 4;

    if (ws_size >= need1) {
        double* Ktab   = (double*)((char*)d_ws + ktab_off);
        int*    hist   = (int*)   ((char*)d_ws + hist_off);
        int*    bbase  = (int*)   ((char*)d_ws + bbase_off);
        int*    hdr    = (int*)   ((char*)d_ws + hdr_off);
        double* diag   = (double*)((char*)d_ws + diag_off);
        double* dpart  = (double*)((char*)d_ws + dpart_off);
        double* A0d    = (double*)((char*)d_ws + a0_off);
        float*  chains = (float*) ((char*)d_ws + chains_off);
        float*  strm   = (float*) ((char*)d_ws + streams_off);
        long long nsegw = ((n + NW - 1) / NW + 255) & ~255LL;

        part1<<<NW/4, 256, 0, stream>>>(w, alpha, hist, dpart, n, nsegw);
        scank<<<1, 256, 0, stream>>>(hist, dpart, bbase, hdr, diag);
        part2<<<NW/8, 256, 0, stream>>>(w, alpha, bbase, hdr, strm, n, nsegw, 0);
        part2<<<NW/8, 256, 0, stream>>>(w, alpha, bbase, hdr, strm, n, nsegw, NW/2);
        span0<<<NCH, 64, 0, stream>>>(strm, hdr, A0d);
        dim3 ga((unsigned)ntg, 4);
        passA7<<<ga, 256, 0, stream>>>(strm, hdr, A0d, Ktab, ntg);
        walk2<<<NCH, 64, 0, stream>>>(strm, hdr, A0d, Ktab, chains, ntg);
        fin2<<<1, 1, 0, stream>>>(chains, diag, hdr, alpha, out, n);
    } else {
        float*  chains = (float*)d_ws;
        double* diag   = (double*)((char*)d_ws + 128);
        zero_diag6<<<1, 64, 0, stream>>>(diag);
        diag6<<<1024, 256, 0, stream>>>(w, alpha, diag, (int)(n >> 2), n);
        seq_chains<<<1, 64, 0, stream>>>(w, alpha, chains, n);
        fin_seq<<<1, 1, 0, stream>>>(chains, diag, alpha, out, n);
    }
}

// Round 18
// 551.045 us; speedup vs baseline: 1.0937x; 1.0937x over previous
//
#include <hip/hip_runtime.h>
#include <cstdint>

#define TS 16384           // elements per tile (stream-relative)
#define NSLOT 13           // binade slots per chain; miss => exact span fallback
#define NCH 7
#define NW 4096            // wave-segments for partition (proven R15 config)

// chains: 0:s(-2) 1:s(-1) 2:s(+1) 3:q(-2) 4:q(-1) 5:q(0) 6:q(+1)
// s(0) non-stalling -> f64 in diag; counts -> min(true, 2^24)

// ---- exact f32 bin boundaries via bit-bisection on the np predicate ----
__device__ __forceinline__ void f32_bounds(float a, float& B1, float& B2) {
    unsigned lo = __float_as_uint(__fmul_rn(a, 0.49f));
    unsigned hi = __float_as_uint(__fmul_rn(a, 0.51f));
    while (hi - lo > 1u) {
        const unsigned mid = lo + ((hi - lo) >> 1);
        if (__fdiv_rn(__uint_as_float(mid), a) <= 0.5f) lo = mid; else hi = mid;
    }
    B1 = __uint_as_float(lo);
    lo = __float_as_uint(__fmul_rn(a, 1.49f));
    hi = __float_as_uint(__fmul_rn(a, 1.51f));
    while (hi - lo > 1u) {
        const unsigned mid = lo + ((hi - lo) >> 1);
        if (__fdiv_rn(__uint_as_float(mid), a) < 1.5f) lo = mid; else hi = mid;
    }
    B2 = __uint_as_float(hi);
}

__device__ __forceinline__ int kbin_f(float x, float B1, float B2) {
    if (x >   B1) return 1;
    if (x >= -B1) return 0;
    if (x >  -B2) return -1;
    return -2;
}

__device__ __forceinline__ double wred64(double v) {
#pragma unroll
    for (int d = 32; d >= 1; d >>= 1) v += __shfl_xor(v, d, 64);
    return v;
}
__device__ __forceinline__ int wred32i(int v) {
#pragma unroll
    for (int d = 32; d >= 1; d >>= 1) v += __shfl_xor(v, d, 64);
    return v;
}

__device__ __forceinline__ int expo_bits(double A) {
    const long long b = __double_as_longlong(A);
    return (int)((b >> 52) & 0x7FF) - 1023;
}
__device__ __forceinline__ int emin_of(double A0) {
    if (!(A0 > 0.0)) return 12345;           // invalid -> walker always spans (exact)
    const int e = expo_bits(A0);
    if (e < -100 || e > 100) return 12345;
    return e;
}

// ---- part1: 4 waves/block, wave-private segments, no barriers, no atomics ----
__global__ __launch_bounds__(256) void part1(const float* __restrict__ w,
        const float* __restrict__ alpha, int* __restrict__ hist,
        double* __restrict__ dpart, long long n, long long nsegw)
{
    const float a = alpha[0];
    float B1, B2;
    f32_bounds(a, B1, B2);
    const int wv = threadIdx.x >> 6, lane = threadIdx.x & 63;
    const int sid = blockIdx.x * 4 + wv;
    const long long seg = (long long)sid * nsegw;
    long long send = seg + nsegw; if (send > n) send = n;
    int h0=0,h1=0,h2=0,h3=0;
    double ad=0.0, dd=0.0, s0=0.0;

    for (long long base = seg; base < send; base += 256) {
        const long long i = base + (long long)lane * 4;
        if (i >= send) break;
        float4 v;
        if (i + 3 < send) v = *reinterpret_cast<const float4*>(w + i);
        else {
            v = make_float4(0.f,0.f,0.f,0.f);
            v.x = w[i];
            if (i+1 < send) v.y = w[i+1];
            if (i+2 < send) v.z = w[i+2];
        }
        const float xs[4] = {v.x, v.y, v.z, v.w};
        const int nv = (int)((send - i) < 4 ? (send - i) : 4);
#pragma unroll
        for (int j = 0; j < 4; ++j) {
            if (j >= nv) break;
            const float x = xs[j];
            const int k = kbin_f(x, B1, B2);
            h0 += (k==-2); h1 += (k==-1); h2 += (k==0); h3 += (k==1);
            const float bf = (float)k;
            const float wq = __fmul_rn(bf, a);
            const float d  = __fsub_rn(x, wq);
            ad += (double)fabsf(d);
            dd += (double)__fmul_rn(d, d);
            if (k == 0) s0 += (double)x;
        }
    }

    h0 = wred32i(h0); h1 = wred32i(h1); h2 = wred32i(h2); h3 = wred32i(h3);
    ad = wred64(ad);  dd = wred64(dd);  s0 = wred64(s0);

    if (lane == 0) {
        hist[sid*4 + 0] = h0;
        hist[sid*4 + 1] = h1;
        hist[sid*4 + 2] = h2;
        hist[sid*4 + 3] = h3;
        dpart[sid*4 + 0] = ad;
        dpart[sid*4 + 1] = dd;
        dpart[sid*4 + 2] = s0;
    }
}

// ---- scank: scan histograms + reduce diag partials ----
__global__ __launch_bounds__(256) void scank(const int* __restrict__ hist,
        const double* __restrict__ dpart, int* __restrict__ bbase,
        int* __restrict__ hdr, double* __restrict__ diag)
{
    const int wv = threadIdx.x >> 6, lane = threadIdx.x & 63;
    if (wv < 4) {
        int running = 0;
        for (int c = 0; c < NW/64; ++c) {
            int v = hist[(c*64 + lane)*4 + wv];
            int p = v;
#pragma unroll
            for (int d = 1; d < 64; d <<= 1) {
                int t = __shfl_up(p, d, 64);
                if (lane >= d) p += t;
            }
            bbase[(c*64+lane)*4 + wv] = running + p - v;
            running += __shfl(p, 63, 64);
        }
        if (lane == 0) hdr[wv] = running;      // cnt[b]
    }
    __syncthreads();
    if (threadIdx.x == 0) {                     // base[b], 64-elem aligned
        int b = 0;
        for (int q = 0; q < 4; ++q) { hdr[4+q] = b; b += (hdr[q] + 63) & ~63; }
    }

    // diag partial reduction (ad, dd, s0)
    double a0=0.0, a1=0.0, a2=0.0;
    for (int e = threadIdx.x; e < NW; e += 256) {
        a0 += dpart[e*4+0]; a1 += dpart[e*4+1]; a2 += dpart[e*4+2];
    }
    a0 = wred64(a0); a1 = wred64(a1); a2 = wred64(a2);
    __shared__ double dsh[4][3];
    if (lane == 0) { dsh[wv][0]=a0; dsh[wv][1]=a1; dsh[wv][2]=a2; }
    __syncthreads();
    if (threadIdx.x == 0) {
        diag[0] = dsh[0][0]+dsh[1][0]+dsh[2][0]+dsh[3][0];
        diag[1] = dsh[0][1]+dsh[1][1]+dsh[2][1]+dsh[3][1];
        diag[2] = dsh[0][2]+dsh[1][2]+dsh[2][2]+dsh[3][2];
    }
}

// ---- part2 v5: direct ranked global writes, ONE store per element ----
// offset computed branchlessly (cndmask chain); semantics identical to R14/R15.
__global__ __launch_bounds__(256) void part2(const float* __restrict__ w,
        const float* __restrict__ alpha, const int* __restrict__ bbase,
        const int* __restrict__ hdr, float* __restrict__ streams,
        long long n, long long nsegw)
{
    const float a = alpha[0];
    float B1, B2;
    f32_bounds(a, B1, B2);
    const int wv = threadIdx.x >> 6, lane = threadIdx.x & 63;
    const int sid = blockIdx.x * 4 + wv;
    const unsigned long long ltmask = (1ULL << lane) - 1ULL;

    int run0 = hdr[4+0] + bbase[sid*4 + 0];
    int run1 = hdr[4+1] + bbase[sid*4 + 1];
    int run2 = hdr[4+2] + bbase[sid*4 + 2];
    int run3 = hdr[4+3] + bbase[sid*4 + 3];

    const long long seg = (long long)sid * nsegw;
    long long send = seg + nsegw; if (send > n) send = n;

    for (long long base = seg; base < send; base += 256) {
        const long long i = base + (long long)lane * 4;
        float xs[4]; int kk[4];
        if (i + 3 < send) {
            const float4 v = *reinterpret_cast<const float4*>(w + i);
            xs[0]=v.x; xs[1]=v.y; xs[2]=v.z; xs[3]=v.w;
            kk[0]=kbin_f(xs[0],B1,B2); kk[1]=kbin_f(xs[1],B1,B2);
            kk[2]=kbin_f(xs[2],B1,B2); kk[3]=kbin_f(xs[3],B1,B2);
        } else {
#pragma unroll
            for (int j = 0; j < 4; ++j) {
                const long long idx = i + j;
                if (idx < send) { xs[j] = w[idx]; kk[j] = kbin_f(xs[j],B1,B2); }
                else            { xs[j] = 0.f;   kk[j] = 9; }
            }
        }

        int br0=0,br1=0,br2=0,br3=0;
        int tt0=0,tt1=0,tt2=0,tt3=0;
#pragma unroll
        for (int j = 0; j < 4; ++j) {
            const unsigned long long b0 = __ballot(kk[j] == -2);
            const unsigned long long b1 = __ballot(kk[j] == -1);
            const unsigned long long b2 = __ballot(kk[j] ==  0);
            const unsigned long long b3 = __ballot(kk[j] ==  1);
            br0 += __popcll(b0 & ltmask); tt0 += __popcll(b0);
            br1 += __popcll(b1 & ltmask); tt1 += __popcll(b1);
            br2 += __popcll(b2 & ltmask); tt2 += __popcll(b2);
            br3 += __popcll(b3 & ltmask); tt3 += __popcll(b3);
        }

        int own0=0, own1=0, own2=0, own3=0;
#pragma unroll
        for (int j = 0; j < 4; ++j) {
            const int k = kk[j];
            int off = run3 + br3 + own3;                      // default: bin 3
            off = (k == -2) ? (run0 + br0 + own0) : off;
            off = (k == -1) ? (run1 + br1 + own1) : off;
            off = (k ==  0) ? (run2 + br2 + own2) : off;
            if (k != 9) streams[(long long)off] = xs[j];      // ONE store/elem
            own0 += (k == -2); own1 += (k == -1);
            own2 += (k ==  0); own3 += (k ==  1);
        }
        run0 += tt0; run1 += tt1; run2 += tt2; run3 += tt3;
    }
}

// ---- exact span walker on a stream (proven R9..R15, verbatim) ----
__device__ void span_st(const float* __restrict__ p, int isq,
                        double& A, long long lo, long long hi, int lane)
{
    for (long long base = lo; base < hi; base += 4096) {
        float xs[64];
        const long long e0 = base + (long long)lane * 64;
#pragma unroll
        for (int q4 = 0; q4 < 16; ++q4) {
            const long long fi = e0 + q4 * 4;
            float4 v = make_float4(0.f,0.f,0.f,0.f);
            if (fi + 3 < hi) v = *reinterpret_cast<const float4*>(p + fi);
            else {
                if (fi     < hi) v.x = p[fi];
                if (fi + 1 < hi) v.y = p[fi + 1];
                if (fi + 2 < hi) v.z = p[fi + 2];
            }
            xs[q4*4+0]=v.x; xs[q4*4+1]=v.y; xs[q4*4+2]=v.z; xs[q4*4+3]=v.w;
        }
#pragma unroll
        for (int j = 0; j < 64; ++j) {
            const float x = xs[j];
            xs[j] = isq ? __fmul_rn(x, x) : fabsf(x);
        }

        int C = 0;
        while (C < 64) {
            if (A > 0.0) {
                const int e = ilogb(A);
                const double u  = ldexp(1.0, e - 23);
                const double Bb = ldexp(1.0, e + 1);
                const double sc = ldexp(1.0, 23 - e);
                double kd = 0.0;
                if (lane >= C) {
#pragma unroll
                    for (int j = 0; j < 64; ++j) kd += rint((double)xs[j] * sc);
                }
                const bool big = kd >= 1099511627776.0;   // 2^40
                double pp = kd;
#pragma unroll
                for (int d = 1; d < 64; d <<= 1) {
                    double tt = __shfl_up(pp, d, 64);
                    if (lane >= d) pp += tt;
                }
                const bool cross = (lane >= C) && (big || (A + u * pp >= Bb));
                const unsigned long long bal = __ballot(cross);
                if (bal == 0ULL) {
                    A = A + u * __shfl(pp, 63);
                    break;
                }
                const int F = __ffsll((long long)bal) - 1;
                double An = 0.0;
                if (lane == F) {
                    const double Aex = A + u * (pp - kd);
                    float Af = (float)Aex;
#pragma unroll
                    for (int j = 0; j < 64; ++j) Af = __fadd_rn(Af, xs[j]);
                    An = (double)Af;
                }
                A = __shfl(An, F);
                C = F + 1;
            } else {
                bool has = false;
                if (lane >= C) {
#pragma unroll
                    for (int j = 0; j < 64; ++j) has = has || (xs[j] > 0.0f);
                }
                const unsigned long long bal = __ballot(has);
                if (bal == 0ULL) break;
                const int F = __ffsll((long long)bal) - 1;
                double An = 0.0;
                if (lane == F) {
                    float Af = 0.0f;
#pragma unroll
                    for (int j = 0; j < 64; ++j) Af = __fadd_rn(Af, xs[j]);
                    An = (double)Af;
                }
                A = __shfl(An, F);
                C = F + 1;
            }
        }
    }
}

// ---------------- span0: exact tile-0 chain state per chain ----------------
__global__ __launch_bounds__(64) void span0(const float* __restrict__ streams,
        const int* __restrict__ hdr, double* __restrict__ A0d)
{
    const int ch = blockIdx.x;
    const int STR[NCH] = {0,1,3,0,1,2,3};
    const int ISQ[NCH] = {0,0,0,1,1,1,1};
    const int st = STR[ch];
    const long long cnt = (long long)hdr[st];
    const float* p = streams + hdr[4+st];
    double A = 0.0;
    if (cnt > 0)
        span_st(p, ISQ[ch], A, 0LL, (TS < cnt ? (long long)TS : cnt), threadIdx.x);
    if (threadIdx.x == 0) A0d[ch] = A;
}

// ---- passA: fused s+q per stream, 13 slots, FLOAT accumulators ----
template<int HASS>
__device__ __forceinline__ void passA_two(const float* __restrict__ p,
        long long cnt, double* __restrict__ krowS, double* __restrict__ krowQ,
        float baseS, float baseQ, long long ntg, long long tile)
{
    const long long lo = tile * TS;
    long long hi = lo + TS; if (hi > cnt) hi = cnt;

    float scS[NSLOT], scQ[NSLOT];
    scS[0] = baseS; scQ[0] = baseQ;
#pragma unroll
    for (int s = 1; s < NSLOT; ++s) { scS[s] = scS[s-1]*0.5f; scQ[s] = scQ[s-1]*0.5f; }
    float accS[NSLOT], accQ[NSLOT];
#pragma unroll
    for (int s = 0; s < NSLOT; ++s) { accS[s] = 0.f; accQ[s] = 0.f; }

    const int tid = threadIdx.x;
    for (long long i = lo + (long long)tid*4; i < hi; i += 256*4) {
        float4 v;
        if (i + 3 < hi) v = *reinterpret_cast<const float4*>(p + i);
        else {
            v = make_float4(0.f,0.f,0.f,0.f);
            v.x = p[i];
            if (i+1 < hi) v.y = p[i+1];
            if (i+2 < hi) v.z = p[i+2];
        }
        const float xsv[4] = {v.x, v.y, v.z, v.w};
#pragma unroll
        for (int j = 0; j < 4; ++j) {
            const float x  = xsv[j];
            const float xq = __fmul_rn(x, x);
            if (HASS) {
                const float ax = fabsf(x);
#pragma unroll
                for (int s = 0; s < NSLOT; ++s)
                    accS[s] += rintf(ax * scS[s]);
            }
#pragma unroll
            for (int s = 0; s < NSLOT; ++s)
                accQ[s] += rintf(xq * scQ[s]);
        }
    }

    __shared__ double lred[4][2*NSLOT];
    const int lane = tid & 63, wv = tid >> 6;
#pragma unroll
    for (int s = 0; s < NSLOT; ++s) {
        double rs = wred64((double)accS[s]);
        double rq = wred64((double)accQ[s]);
        if (lane == 0) { lred[wv][s] = rs; lred[wv][NSLOT+s] = rq; }
    }
    __syncthreads();
    if (tid < 2*NSLOT) {
        const double sum = lred[0][tid]+lred[1][tid]+lred[2][tid]+lred[3][tid];
        if (tid < NSLOT) {
            if (HASS) krowS[(long long)tid * ntg + tile] = sum;
        } else {
            krowQ[(long long)(tid-NSLOT) * ntg + tile] = sum;
        }
    }
}

__global__ __launch_bounds__(256) void passA7(const float* __restrict__ streams,
        const int* __restrict__ hdr, const double* __restrict__ A0d,
        double* __restrict__ Ktab, long long ntg)
{
    const int st = blockIdx.y;                    // stream 0..3
    const int SCH[4] = {0, 1, -1, 2};             // s-chain per stream
    const int QCH[4] = {3, 4,  5, 6};             // q-chain per stream
    const long long cnt = (long long)hdr[st];
    const long long tile = blockIdx.x;
    if (tile * TS >= cnt) return;
    const float* p = streams + hdr[4+st];

    const int qch = QCH[st];
    const int emQ = emin_of(A0d[qch]);
    const float baseQ = (emQ == 12345) ? 0.0f : ldexpf(1.0f, 23 - emQ);
    double* krowQ = Ktab + (long long)qch * NSLOT * ntg;

    if (SCH[st] >= 0) {
        const int sch = SCH[st];
        const int emS = emin_of(A0d[sch]);
        const float baseS = (emS == 12345) ? 0.0f : ldexpf(1.0f, 23 - emS);
        double* krowS = Ktab + (long long)sch * NSLOT * ntg;
        passA_two<1>(p, cnt, krowS, krowQ, baseS, baseQ, ntg, tile);
    } else {
        passA_two<0>(p, cnt, nullptr, krowQ, 0.0f, baseQ, ntg, tile);
    }
}

// ---- walk: windowed binade walk, 128-tile windows (proven R15) ----
__global__ __launch_bounds__(64) void walk2(const float* __restrict__ streams,
        const int* __restrict__ hdr, const double* __restrict__ A0d,
        const double* __restrict__ Ktab, float* __restrict__ chains, long long ntg)
{
    const int ch = blockIdx.x;
    const int lane = threadIdx.x;
    const int STR[NCH]  = {0,1,3,0,1,2,3};
    const int ISQ[NCH]  = {0,0,0,1,1,1,1};
    const int OSLOT[NCH]= {0,1,3,4,5,6,7};
    const int st = STR[ch], isq = ISQ[ch];
    const long long cnt = (long long)hdr[st];
    const float* p = streams + hdr[4+st];
    const long long ntiles = (cnt + TS - 1) / TS;
    const double* krow = Ktab + (long long)ch * NSLOT * ntg;
    const int em = emin_of(A0d[ch]);

    double A = A0d[ch];
    long long t = 1;
    while (t < ntiles) {
        if (A > 0.0 && em != 12345) {
            const int e = expo_bits(A);
            const int slot = e - em;
            if (slot >= 0 && slot < NSLOT) {
                const long long wt0 = t + lane;
                const long long wt1 = t + 64 + lane;
                double Kv0 = (wt0 < ntiles) ? krow[(long long)slot * ntg + wt0] : 0.0;
                double Kv1 = (wt1 < ntiles) ? krow[(long long)slot * ntg + wt1] : 0.0;
                double P0 = Kv0;
#pragma unroll
                for (int d = 1; d < 64; d <<= 1) {
                    double tt = __shfl_up(P0, d, 64);
                    if (lane >= d) P0 += tt;
                }
                const double tot0 = __shfl(P0, 63);
                double P1 = Kv1;
#pragma unroll
                for (int d = 1; d < 64; d <<= 1) {
                    double tt = __shfl_up(P1, d, 64);
                    if (lane >= d) P1 += tt;
                }
                P1 += tot0;
                const double u  = ldexp(1.0, e - 23);
                const double Bb = ldexp(1.0, e + 1);
                const unsigned long long bal0 = __ballot(A + u * P0 > Bb);
                const unsigned long long bal1 = __ballot(A + u * P1 > Bb);
                if (bal0 == 0ULL && bal1 == 0ULL) {      // whole 128 consumable: exact
                    A += u * __shfl(P1, 63);
                    t += 128;
                    continue;
                }
                const int F = (bal0 != 0ULL) ? (__ffsll((long long)bal0) - 1)
                                             : (64 + __ffsll((long long)bal1) - 1);
                if (F > 0) {                              // consume tiles t..t+F-1
                    const double cv = (F <= 64) ? __shfl(P0, F - 1)
                                                : __shfl(P1, F - 65);
                    A += u * cv;
                    t += F;
                }
                const long long lo = t * (long long)TS;   // crossing tile: exact
                long long hi = lo + TS; if (hi > cnt) hi = cnt;
                span_st(p, isq, A, lo, hi, lane);
                ++t;
                continue;
            }
        }
        const long long lo = t * (long long)TS;
        long long hi = lo + TS; if (hi > cnt) hi = cnt;
        span_st(p, isq, A, lo, hi, lane);
        ++t;
    }
    if (lane == 0) chains[OSLOT[ch]] = (float)A;
}

// ---------------- finalize (proven R9..R15) ----------------
__global__ void fin2(const float* __restrict__ chains,
                     const double* __restrict__ diag,
                     const int* __restrict__ hdr,
                     const float* __restrict__ alpha,
                     float* __restrict__ out, long long n)
{
    const float a = alpha[0];
    const float s_np[4]  = { -chains[0], -chains[1], (float)diag[2], chains[3] };
    const float sq_np[4] = {  chains[4],  chains[5],  chains[6],     chains[7] };
    float tmse = 0.f, tvar = 0.f;
#pragma unroll
    for (int b = 0; b < 4; ++b) {
        float cnt = fminf((float)hdr[b], 16777216.0f);
        float safe = fmaxf(cnt, 1.0f);
        float mean = __fdiv_rn(s_np[b], safe);
        float var  = __fsub_rn(__fdiv_rn(sq_np[b], safe), __fmul_rn(mean, mean));
        float lvl  = __fmul_rn((float)(b - 2), a);
        float e    = __fsub_rn(mean, lvl);
        if (cnt > 0.f)  tmse = __fadd_rn(tmse, __fmul_rn(e, e));
        if (cnt >= 2.f) tvar = __fadd_rn(tvar, var);
    }
    out[0] = __fadd_rn(tmse, tvar);
    out[1] = tmse;
    out[2] = tvar;
    out[3] = (float)(diag[1] / (double)n);
    out[4] = (float)(diag[0] / (double)n);
}

// ================= TIER 3: R6 bit-exact serial fallback =================
__global__ __launch_bounds__(64) void zero_diag6(double* __restrict__ diag) {
    if (threadIdx.x < 6) diag[threadIdx.x] = 0.0;
}
__global__ __launch_bounds__(256) void diag6(const float* __restrict__ w,
        const float* __restrict__ alpha, double* __restrict__ diag, int n4, long long n)
{
    const float a = alpha[0];
    float ad = 0.f, dd = 0.f; int c0=0,c1=0,c2=0,c3=0;
    auto pe = [&](float x) {
        float r = __fdiv_rn(x, a);
        float cl = fminf(1.0f, fmaxf(-2.0f, r));
        float bf = rintf(cl); int k = (int)bf;
        float wq = __fmul_rn(bf, a); float d = __fsub_rn(x, wq);
        ad = __fadd_rn(ad, fabsf(d)); dd = __fadd_rn(dd, __fmul_rn(d, d));
        if (k==-2) c0++; else if (k==-1) c1++; else if (k==0) c2++; else c3++;
    };
    const float4* w4 = reinterpret_cast<const float4*>(w);
    const int stride = gridDim.x * 256;
    for (int i = blockIdx.x * 256 + threadIdx.x; i < n4; i += stride) {
        float4 v = w4[i]; pe(v.x); pe(v.y); pe(v.z); pe(v.w);
    }
    if (blockIdx.x == 0 && threadIdx.x == 0)
        for (long long i = (long long)n4 * 4; i < n; ++i) pe(w[i]);
    double vals[6] = {(double)ad,(double)dd,(double)c0,(double)c1,(double)c2,(double)c3};
    __shared__ double red[256];
    const int tid = threadIdx.x;
#pragma unroll
    for (int j = 0; j < 6; ++j) {
        red[tid] = vals[j]; __syncthreads();
        for (int s = 128; s > 0; s >>= 1) { if (tid < s) red[tid] += red[tid+s]; __syncthreads(); }
        if (tid == 0) atomicAdd(&diag[j], red[0]);
        __syncthreads();
    }
}
__global__ __launch_bounds__(64) void seq_chains(const float* __restrict__ w,
        const float* __restrict__ alpha, float* __restrict__ chains, long long n)
{
    const float a = alpha[0];
    const int lane = threadIdx.x; const int myrow = lane & 7;
    __shared__ float val[8][64];
    float acc = 0.0f;
    const long long ntl = (n + 63) / 64;
    float x_next = (lane < n) ? w[lane] : 0.0f;
    for (long long t = 0; t < ntl; ++t) {
        float x = x_next;
        { long long idxn = (t + 1) * 64 + lane; x_next = (idxn < n) ? w[idxn] : 0.0f; }
        const long long idx = t * 64 + lane;
        const bool valid = (idx < n);
        float r = __fdiv_rn(x, a);
        float cl = fminf(1.0f, fmaxf(-2.0f, r));
        int k = (int)rintf(cl); int row = k + 2;
        float xx = __fmul_rn(x, x);
#pragma unroll
        for (int b = 0; b < 4; ++b) {
            val[b][lane]     = (valid && row == b) ? x  : 0.0f;
            val[4 + b][lane] = (valid && row == b) ? xx : 0.0f;
        }
        __syncthreads();
        if (lane < 8) {
#pragma unroll
            for (int e4i = 0; e4i < 16; ++e4i) {
                float4 v = *reinterpret_cast<const float4*>(&val[myrow][e4i * 4]);
                acc = __fadd_rn(acc, v.x); acc = __fadd_rn(acc, v.y);
                acc = __fadd_rn(acc, v.z); acc = __fadd_rn(acc, v.w);
            }
        }
        __syncthreads();
    }
    if (lane < 8) chains[lane] = acc;
}
__global__ void fin_seq(const float* __restrict__ chains, const double* __restrict__ diag,
                        const float* __restrict__ alpha, float* __restrict__ out, long long n)
{
    const float a = alpha[0];
    float tmse = 0.0f, tvar = 0.0f;
#pragma unroll
    for (int b = 0; b < 4; ++b) {
        float cnt = fminf((float)diag[2 + b], 16777216.0f);
        float safe = fmaxf(cnt, 1.0f);
        float mean = __fdiv_rn(chains[b], safe);
        float var  = __fsub_rn(__fdiv_rn(chains[4 + b], safe), __fmul_rn(mean, mean));
        float lvl  = __fmul_rn((float)(b - 2), a);
        float e    = __fsub_rn(mean, lvl);
        if (cnt > 0.0f)  tmse = __fadd_rn(tmse, __fmul_rn(e, e));
        if (cnt >= 2.0f) tvar = __fadd_rn(tvar, var);
    }
    out[0] = __fadd_rn(tmse, tvar);
    out[1] = tmse; out[2] = tvar;
    out[3] = (float)(diag[1] / (double)n);
    out[4] = (float)(diag[0] / (double)n);
}

// ---------------- launcher ----------------
extern "C" void kernel_launch(void* const* d_in, const int* in_sizes, int n_in,
                              void* d_out, int out_size, void* d_ws, size_t ws_size,
                              hipStream_t stream) {
    const float* w     = (const float*)d_in[0];
    const float* alpha = (const float*)d_in[1];
    float* out = (float*)d_out;
    const long long n = (long long)in_sizes[0];
    const long long ntg = (n + TS - 1) / TS;

    size_t off = 0;
    const size_t ktab_off = off;   off += (size_t)NCH * NSLOT * ntg * 8;
    const size_t hist_off = off;   off += (size_t)NW * 4 * 4;
    const size_t bbase_off = off;  off += (size_t)NW * 4 * 4;
    const size_t hdr_off = off;    off += 8 * 4;
    const size_t diag_off = (off + 7) & ~(size_t)7;  off = diag_off + 8 * 8;
    const size_t dpart_off = off;  off += (size_t)NW * 4 * 8;
    const size_t a0_off = off;     off += 8 * 8;
    const size_t chains_off = off; off += 8 * 4;
    const size_t streams_off = (off + 255) & ~(size_t)255;
    const size_t need1 = streams_off + ((size_t)n + 512) * 4;

    if (ws_size >= need1) {
        double* Ktab   = (double*)((char*)d_ws + ktab_off);
        int*    hist   = (int*)   ((char*)d_ws + hist_off);
        int*    bbase  = (int*)   ((char*)d_ws + bbase_off);
        int*    hdr    = (int*)   ((char*)d_ws + hdr_off);
        double* diag   = (double*)((char*)d_ws + diag_off);
        double* dpart  = (double*)((char*)d_ws + dpart_off);
        double* A0d    = (double*)((char*)d_ws + a0_off);
        float*  chains = (float*) ((char*)d_ws + chains_off);
        float*  strm   = (float*) ((char*)d_ws + streams_off);
        long long nsegw = ((n + NW - 1) / NW + 255) & ~255LL;

        part1<<<NW/4, 256, 0, stream>>>(w, alpha, hist, dpart, n, nsegw);
        scank<<<1, 256, 0, stream>>>(hist, dpart, bbase, hdr, diag);
        part2<<<NW/4, 256, 0, stream>>>(w, alpha, bbase, hdr, strm, n, nsegw);
        span0<<<NCH, 64, 0, stream>>>(strm, hdr, A0d);
        dim3 ga((unsigned)ntg, 4);
        passA7<<<ga, 256, 0, stream>>>(strm, hdr, A0d, Ktab, ntg);
        walk2<<<NCH, 64, 0, stream>>>(strm, hdr, A0d, Ktab, chains, ntg);
        fin2<<<1, 1, 0, stream>>>(chains, diag, hdr, alpha, out, n);
    } else {
        float*  chains = (float*)d_ws;
        double* diag   = (double*)((char*)d_ws + 128);
        zero_diag6<<<1, 64, 0, stream>>>(diag);
        diag6<<<1024, 256, 0, stream>>>(w, alpha, diag, (int)(n >> 2), n);
        seq_chains<<<1, 64, 0, stream>>>(w, alpha, chains, n);
        fin_seq<<<1, 1, 0, stream>>>(chains, diag, alpha, out, n);
    }
}